// Round 2
// baseline (557.615 us; speedup 1.0000x reference)
//
#include <hip/hip_runtime.h>
#include <hip/hip_bf16.h>
#include <cstdint>

// DynamicPlasticityModule collapsed:
//   combined = x @ A^T + c1,  A  = Wc_eff @ Wp,  Wc_eff[j,:] = gate[j>>5]*Wc[j,:]
//   out      = x @ B2^T + c2, B2 = Wo @ A
// Single fused GEMM x[131072,256] @ Wbig^T[512,256], bf16 MFMA, fp32 accum.
// R1: no-LDS GEMM — fragments loaded direct from global (x via L3, W via L2),
//     fp32->bf16 via v_cvt_pk_bf16_f32 (1 instr / 2 elem), nontemporal stores.

#define BATCH 131072
#define TAIL ((size_t)2 * BATCH * 256)

typedef unsigned short u16;
typedef __attribute__((ext_vector_type(8))) short short8;
typedef __attribute__((ext_vector_type(4))) float floatx4;

__device__ __forceinline__ short f2bf(float f) {
    union { float f; unsigned u; } v; v.f = f;
    unsigned u = v.u;
    u += 0x7fffu + ((u >> 16) & 1u);   // RNE
    return (short)(u >> 16);
}

// pack two fp32 -> packed bf16 (lo, hi) in one instr where available
__device__ __forceinline__ unsigned cvt2(float lo, float hi) {
#if __has_builtin(__builtin_amdgcn_cvt_pk_bf16_f32)
    auto p = __builtin_amdgcn_cvt_pk_bf16_f32(lo, hi);
    union { decltype(p) p; unsigned u; } c; c.p = p; return c.u;
#else
    union { float f; unsigned u; } a, b; a.f = lo; b.f = hi;
    // truncation pack: result = {lo.bytes[2,3], hi.bytes[2,3]}
    return __builtin_amdgcn_perm(b.u, a.u, 0x07060302);
#endif
}

__device__ __forceinline__ float gate_for(const float* pre, const float* post, int kc) {
    float na = 0.f, nb = 0.f, dp = 0.f;
    for (int i = 0; i < 32; ++i) {
        float a = pre[kc * 256 + i], b = post[kc * 32 + i];
        na += a * a; nb += b * b; dp += a * b;
    }
    float denom = fmaxf(sqrtf(na), 1e-12f) * fmaxf(sqrtf(nb), 1e-12f);
    float sim = dp / denom;
    float align = 1.f / (1.f + expf(-sim));       // GAIN = 1
    return (align >= 0.3f) ? align : 0.f;         // THRESH = 0.3
}

// ---------------- k1: alignments / allocation_mask outputs ----------------
__global__ void k_align(const float* __restrict__ pre, const float* __restrict__ post,
                        float* __restrict__ out_tail) {
    int k = threadIdx.x;
    if (k < 8) {
        float g = gate_for(pre, post, k);
        out_tail[k] = g;           // alignments = align*(align>=thresh) == gate
        out_tail[8 + k] = 1.f;     // allocation_mask
    }
}

// ---------------- k2: A = Wc_eff @ Wp (fp32), c1 = Wc_eff @ bp ----------------
__global__ __launch_bounds__(256) void k_makeA(
        const float* __restrict__ Wc, const float* __restrict__ Wp,
        const float* __restrict__ bp, const float* __restrict__ pre,
        const float* __restrict__ post,
        float* __restrict__ A, float* __restrict__ bias512, u16* __restrict__ Wbig) {
    int j = blockIdx.x, t = threadIdx.x;
    __shared__ float wc[256];
    __shared__ float red[256];
    __shared__ float gsh;
    if (t == 0) gsh = gate_for(pre, post, j >> 5);
    float v = Wc[j * 256 + t];
    wc[t] = v;
    red[t] = v * bp[t];
    __syncthreads();
    float g = gsh;
    for (int s = 128; s > 0; s >>= 1) {
        if (t < s) red[t] += red[t + s];
        __syncthreads();
    }
    if (t == 0) bias512[256 + j] = g * red[0];   // c1[j]
    float acc = 0.f;
#pragma unroll 16
    for (int i = 0; i < 256; ++i) acc += wc[i] * Wp[i * 256 + t];
    acc *= g;
    A[j * 256 + t] = acc;
    Wbig[(256 + j) * 256 + t] = (u16)f2bf(acc);  // rows 256..511 of Wbig = A
}

// ---------------- k3: B2 = Wo @ A (fp32), c2 = Wo @ c1 + bo ----------------
__global__ __launch_bounds__(256) void k_makeB2(
        const float* __restrict__ Wo, const float* __restrict__ bo,
        const float* __restrict__ A, float* __restrict__ bias512,
        u16* __restrict__ Wbig) {
    int tt = blockIdx.x, t = threadIdx.x;
    __shared__ float wo[256];
    __shared__ float red[256];
    float v = Wo[tt * 256 + t];
    wo[t] = v;
    red[t] = v * bias512[256 + t];   // c1
    __syncthreads();
    for (int s = 128; s > 0; s >>= 1) {
        if (t < s) red[t] += red[t + s];
        __syncthreads();
    }
    if (t == 0) bias512[tt] = red[0] + bo[tt];   // c2[tt]
    float acc = 0.f;
#pragma unroll 16
    for (int i = 0; i < 256; ++i) acc += wo[i] * A[i * 256 + t];
    Wbig[tt * 256 + t] = (u16)f2bf(acc);         // rows 0..255 of Wbig = B2
}

// ---------------- k4: no-LDS direct-register MFMA GEMM ----------------
union FragAB { short8 s; unsigned u[4]; };

__global__ __launch_bounds__(256, 2) void k_gemm(
        const float* __restrict__ x, const u16* __restrict__ Wbig,
        const float* __restrict__ bias512, float* __restrict__ out) {
    const int tid = threadIdx.x;
    const int wave = tid >> 6, lane = tid & 63;
    const int lr = lane & 15, quad = lane >> 4;
    const int b = blockIdx.x;
    // 32-block groups: 8 mtiles x 4 ntiles; an mtile's 4 ntiles share b%8 -> same XCD
    const int mtile = ((b >> 5) << 3) + (b & 7);
    const int ntile = (b >> 3) & 3;
    const int m0 = mtile * 128, n0 = ntile * 128;
    const int wm = wave >> 1, wn = wave & 1;

    floatx4 acc[4][4];
#pragma unroll
    for (int i = 0; i < 4; ++i)
#pragma unroll
        for (int j = 0; j < 4; ++j) acc[i][j] = (floatx4)0.f;

    // A fragment bases: lane holds A[row=lr][k=quad*8..+8] (fp32, 32 B)
    const float* abase[4];
#pragma unroll
    for (int i = 0; i < 4; ++i)
        abase[i] = x + (size_t)(m0 + wm * 64 + i * 16 + lr) * 256 + quad * 8;
    // B fragment bases: lane holds W[n=lr'][k=quad*8..+8] (bf16, 16 B)
    const u16* bbase[4];
#pragma unroll
    for (int j = 0; j < 4; ++j)
        bbase[j] = Wbig + (size_t)(n0 + wn * 64 + j * 16 + lr) * 256 + quad * 8;

#pragma unroll
    for (int kk = 0; kk < 8; ++kk) {
        FragAB fa[4], fb[4];
        float4 a0[4], a1[4];
#pragma unroll
        for (int i = 0; i < 4; ++i) {
            a0[i] = *(const float4*)(abase[i] + kk * 32);
            a1[i] = *(const float4*)(abase[i] + kk * 32 + 4);
        }
#pragma unroll
        for (int j = 0; j < 4; ++j)
            fb[j].s = *(const short8*)(bbase[j] + kk * 32);
#pragma unroll
        for (int i = 0; i < 4; ++i) {
            fa[i].u[0] = cvt2(a0[i].x, a0[i].y);
            fa[i].u[1] = cvt2(a0[i].z, a0[i].w);
            fa[i].u[2] = cvt2(a1[i].x, a1[i].y);
            fa[i].u[3] = cvt2(a1[i].z, a1[i].w);
        }
#pragma unroll
        for (int i = 0; i < 4; ++i)
#pragma unroll
            for (int j = 0; j < 4; ++j)
                acc[i][j] = __builtin_amdgcn_mfma_f32_16x16x32_bf16(fa[i].s, fb[j].s, acc[i][j], 0, 0, 0);
    }

    float biasj[4];
#pragma unroll
    for (int j = 0; j < 4; ++j) biasj[j] = bias512[n0 + wn * 64 + j * 16 + lr];

    // epilogue: C/D layout col=lane&15, row=quad*4+reg (m89-verified)
    float* obase = out + ((ntile < 2) ? (size_t)0 : ((size_t)BATCH * 256));
    const int ncol0 = n0 - ((ntile < 2) ? 0 : 256);
#pragma unroll
    for (int i = 0; i < 4; ++i) {
#pragma unroll
        for (int j = 0; j < 4; ++j) {
            const int col = ncol0 + wn * 64 + j * 16 + lr;
#pragma unroll
            for (int r = 0; r < 4; ++r) {
                const size_t row = (size_t)(m0 + wm * 64 + i * 16 + quad * 4 + r);
                __builtin_nontemporal_store(acc[i][j][r] + biasj[j], &obase[row * 256 + col]);
            }
        }
    }
}

extern "C" void kernel_launch(void* const* d_in, const int* in_sizes, int n_in,
                              void* d_out, int out_size, void* d_ws, size_t ws_size,
                              hipStream_t stream) {
    const float* x    = (const float*)d_in[0];
    const float* Wp   = (const float*)d_in[1];
    const float* bp   = (const float*)d_in[2];
    const float* pre  = (const float*)d_in[3];
    const float* post = (const float*)d_in[4];
    const float* Wc   = (const float*)d_in[5];
    const float* Wo   = (const float*)d_in[6];
    const float* bo   = (const float*)d_in[7];
    float* out = (float*)d_out;

    char* ws = (char*)d_ws;
    float* bias512 = (float*)(ws + 64);               // 2 KB: [0,256)=c2, [256,512)=c1
    float* A       = (float*)(ws + 4096);             // 256 KB fp32
    u16*  Wbig     = (u16*)(ws + 4096 + 262144);      // 256 KB bf16 [512 x 256]

    float* out_tail = out + TAIL;

    k_align<<<dim3(1), dim3(64), 0, stream>>>(pre, post, out_tail);
    k_makeA<<<dim3(256), dim3(256), 0, stream>>>(Wc, Wp, bp, pre, post, A, bias512, Wbig);
    k_makeB2<<<dim3(256), dim3(256), 0, stream>>>(Wo, bo, A, bias512, Wbig);
    k_gemm<<<dim3(4096), dim3(256), 0, stream>>>(x, Wbig, bias512, out);
}